// Round 1
// baseline (2957.628 us; speedup 1.0000x reference)
//
#include <hip/hip_runtime.h>
#include <cmath>

#define B_   8
#define N_   1024
#define C_   768
#define H_   12
#define D_   64
#define HID_ 3072
#define M_   8192   // B_*N_

__device__ __forceinline__ float gelu_exact(float x) {
    return 0.5f * x * (1.0f + erff(x * 0.70710678118654752f));
}

// ---------------- LayerNorm: one block (256 thr) per row of 768 ----------------
__global__ __launch_bounds__(256)
void ln_kernel(const float* __restrict__ x, const float* __restrict__ g,
               const float* __restrict__ b, float* __restrict__ y)
{
    __shared__ float red[256];
    const long row = blockIdx.x;
    const float* xr = x + row * C_;
    float* yr = y + row * C_;
    const int t = threadIdx.x;
    float v0 = xr[t], v1 = xr[t + 256], v2 = xr[t + 512];
    red[t] = v0 + v1 + v2;
    __syncthreads();
    for (int o = 128; o > 0; o >>= 1) { if (t < o) red[t] += red[t + o]; __syncthreads(); }
    const float mu = red[0] * (1.0f / 768.0f);
    __syncthreads();
    const float d0 = v0 - mu, d1 = v1 - mu, d2 = v2 - mu;
    red[t] = d0 * d0 + d1 * d1 + d2 * d2;
    __syncthreads();
    for (int o = 128; o > 0; o >>= 1) { if (t < o) red[t] += red[t + o]; __syncthreads(); }
    const float rstd = rsqrtf(red[0] * (1.0f / 768.0f) + 1e-5f);
    yr[t]       = d0 * rstd * g[t]       + b[t];
    yr[t + 256] = d1 * rstd * g[t + 256] + b[t + 256];
    yr[t + 512] = d2 * rstd * g[t + 512] + b[t + 512];
}

// ---------------- Generic tiled GEMM ----------------
// C = alpha * A @ op(B) (+bias) (+res), optional exact-GELU.
// TRANSB=true : B is [Ncol, K] row-major (compute A @ B^T)  -- weight matrices
// TRANSB=false: B is [K, Ncol] row-major (compute A @ B)    -- PV
// Batched over blockIdx.z: z -> (zb = z/H_, zh = z%H_), per-operand strides.
template<bool TRANSB, int ACT>
__global__ __launch_bounds__(256)
void gemm_tile(const float* __restrict__ A, int lda, long sAb, long sAh,
               const float* __restrict__ Bm, int ldb, long sBb, long sBh,
               const float* __restrict__ bias,
               const float* __restrict__ res, int ldres,
               float* __restrict__ Cm, int ldc, long sCb, long sCh,
               int M, int Ncol, int K, float alpha)
{
    constexpr int BM = 64, BN = 64, BK = 32;
    __shared__ float As[BK][BM + 1];
    __shared__ float Bs[BK][BN + 1];
    const int z = blockIdx.z;
    const int zb = z / H_, zh = z % H_;
    const float* Ab = A  + zb * sAb + zh * sAh;
    const float* Bb = Bm + zb * sBb + zh * sBh;
    float*       Cb = Cm + zb * sCb + zh * sCh;
    const int m0 = blockIdx.y * BM;
    const int n0 = blockIdx.x * BN;
    const int tid = threadIdx.x;
    const int tx = tid & 15, ty = tid >> 4;
    float acc[4][4] = {};

    for (int k0 = 0; k0 < K; k0 += BK) {
        {   // A tile: BM x BK, transposed into As[k][m]
            const int row = tid >> 2;
            const int col = (tid & 3) * 8;
            const float* src = Ab + (long)(m0 + row) * lda + (k0 + col);
            float4 u0 = *(const float4*)(src);
            float4 u1 = *(const float4*)(src + 4);
            As[col + 0][row] = u0.x; As[col + 1][row] = u0.y;
            As[col + 2][row] = u0.z; As[col + 3][row] = u0.w;
            As[col + 4][row] = u1.x; As[col + 5][row] = u1.y;
            As[col + 6][row] = u1.z; As[col + 7][row] = u1.w;
        }
        if constexpr (TRANSB) {
            const int row = tid >> 2;          // output-col index
            const int col = (tid & 3) * 8;     // k index
            const float* src = Bb + (long)(n0 + row) * ldb + (k0 + col);
            float4 u0 = *(const float4*)(src);
            float4 u1 = *(const float4*)(src + 4);
            Bs[col + 0][row] = u0.x; Bs[col + 1][row] = u0.y;
            Bs[col + 2][row] = u0.z; Bs[col + 3][row] = u0.w;
            Bs[col + 4][row] = u1.x; Bs[col + 5][row] = u1.y;
            Bs[col + 6][row] = u1.z; Bs[col + 7][row] = u1.w;
        } else {
            const int kk = tid >> 3;           // k index 0..31
            const int nn = (tid & 7) * 8;      // col
            const float* src = Bb + (long)(k0 + kk) * ldb + (n0 + nn);
            float4 u0 = *(const float4*)(src);
            float4 u1 = *(const float4*)(src + 4);
            Bs[kk][nn + 0] = u0.x; Bs[kk][nn + 1] = u0.y;
            Bs[kk][nn + 2] = u0.z; Bs[kk][nn + 3] = u0.w;
            Bs[kk][nn + 4] = u1.x; Bs[kk][nn + 5] = u1.y;
            Bs[kk][nn + 6] = u1.z; Bs[kk][nn + 7] = u1.w;
        }
        __syncthreads();
        #pragma unroll
        for (int k = 0; k < BK; k++) {
            float a[4], bv[4];
            #pragma unroll
            for (int i = 0; i < 4; i++) a[i]  = As[k][ty * 4 + i];
            #pragma unroll
            for (int j = 0; j < 4; j++) bv[j] = Bs[k][tx * 4 + j];
            #pragma unroll
            for (int i = 0; i < 4; i++)
                #pragma unroll
                for (int j = 0; j < 4; j++)
                    acc[i][j] += a[i] * bv[j];
        }
        __syncthreads();
    }

    #pragma unroll
    for (int i = 0; i < 4; i++) {
        const long r = m0 + ty * 4 + i;
        #pragma unroll
        for (int j = 0; j < 4; j++) {
            const int c = n0 + tx * 4 + j;
            float v = acc[i][j] * alpha;
            if (bias) v += bias[c];
            if (res)  v += res[r * (long)ldres + c];
            if (ACT == 1) v = gelu_exact(v);
            Cb[r * (long)ldc + c] = v;
        }
    }
}

// ---------------- Softmax over last dim (1024), in place ----------------
__global__ __launch_bounds__(256)
void softmax_kernel(float* __restrict__ S)
{
    __shared__ float red[256];
    const long row = blockIdx.x;
    float* p = S + row * (long)N_ + threadIdx.x * 4;
    const int t = threadIdx.x;
    float4 v = *(float4*)p;
    red[t] = fmaxf(fmaxf(v.x, v.y), fmaxf(v.z, v.w));
    __syncthreads();
    for (int o = 128; o > 0; o >>= 1) { if (t < o) red[t] = fmaxf(red[t], red[t + o]); __syncthreads(); }
    const float mx = red[0];
    __syncthreads();
    v.x = __expf(v.x - mx); v.y = __expf(v.y - mx);
    v.z = __expf(v.z - mx); v.w = __expf(v.w - mx);
    red[t] = v.x + v.y + v.z + v.w;
    __syncthreads();
    for (int o = 128; o > 0; o >>= 1) { if (t < o) red[t] += red[t + o]; __syncthreads(); }
    const float inv = 1.0f / red[0];
    v.x *= inv; v.y *= inv; v.z *= inv; v.w *= inv;
    *(float4*)p = v;
}

// ---------------- Head-mix (1x1 conv over H) + BatchNorm(eval), in place ----------------
// One block per (b,n); thread t handles m = t*4 .. t*4+3 for all 12 heads.
__global__ __launch_bounds__(256)
void mixbn_kernel(float* __restrict__ S,
                  const float* __restrict__ cw, const float* __restrict__ cb,
                  const float* __restrict__ bg, const float* __restrict__ bb,
                  const float* __restrict__ brm, const float* __restrict__ brv)
{
    __shared__ float w[H_][H_];
    __shared__ float cbias[H_], sc[H_], sh[H_];
    const int t = threadIdx.x;
    if (t < H_ * H_) w[t / H_][t % H_] = cw[t];
    if (t < H_) {
        cbias[t] = cb[t];
        const float s = bg[t] * rsqrtf(brv[t] + 1e-5f);
        sc[t] = s;
        sh[t] = bb[t] - brm[t] * s;
    }
    __syncthreads();
    const long bn = blockIdx.x;                 // b*N + n
    const long b = bn >> 10, n = bn & 1023;
    float* base = S + b * (long)H_ * N_ * N_ + n * (long)N_ + t * 4;
    float4 p[H_];
    #pragma unroll
    for (int h = 0; h < H_; h++) p[h] = *(float4*)(base + (long)h * N_ * N_);
    #pragma unroll
    for (int o = 0; o < H_; o++) {
        float4 a;
        a.x = cbias[o]; a.y = cbias[o]; a.z = cbias[o]; a.w = cbias[o];
        #pragma unroll
        for (int h = 0; h < H_; h++) {
            const float wv = w[o][h];
            a.x += wv * p[h].x; a.y += wv * p[h].y;
            a.z += wv * p[h].z; a.w += wv * p[h].w;
        }
        a.x = a.x * sc[o] + sh[o]; a.y = a.y * sc[o] + sh[o];
        a.z = a.z * sc[o] + sh[o]; a.w = a.w * sc[o] + sh[o];
        *(float4*)(base + (long)o * N_ * N_) = a;
    }
}

// ---------------- launch ----------------
extern "C" void kernel_launch(void* const* d_in, const int* in_sizes, int n_in,
                              void* d_out, int out_size, void* d_ws, size_t ws_size,
                              hipStream_t stream)
{
    const float* inp    = (const float*)d_in[0];
    const float* ln1_g  = (const float*)d_in[1];
    const float* ln1_b  = (const float*)d_in[2];
    const float* qkv_w  = (const float*)d_in[3];
    const float* conv_w = (const float*)d_in[4];
    const float* conv_b = (const float*)d_in[5];
    const float* bn_g   = (const float*)d_in[6];
    const float* bn_b   = (const float*)d_in[7];
    const float* bn_rm  = (const float*)d_in[8];
    const float* bn_rv  = (const float*)d_in[9];
    const float* proj_w = (const float*)d_in[10];
    const float* proj_b = (const float*)d_in[11];
    const float* ln2_g  = (const float*)d_in[12];
    const float* ln2_b  = (const float*)d_in[13];
    const float* fc1_w  = (const float*)d_in[14];
    const float* fc1_b  = (const float*)d_in[15];
    const float* fc2_w  = (const float*)d_in[16];
    const float* fc2_b  = (const float*)d_in[17];

    float* outx = (float*)d_out;                       // [B,N,C]
    float* attn = outx + (long)M_ * C_;                // [B,H,N,N] (also scratch for S/P)

    float* regA = (float*)d_ws;                        // 6.29M floats: xln -> O -> xln2
    float* regB = regA + (long)M_ * C_;                // 6.29M floats: x residual
    float* regH = regB + (long)M_ * C_;                // 25.17M floats: qkv -> gelu(fc1)
    float* qkv  = regH;

    // 1) LN1: inputs -> regA
    ln_kernel<<<M_, 256, 0, stream>>>(inp, ln1_g, ln1_b, regA);

    // 2) qkv = xln @ qkv_w^T : [8192,2304]
    gemm_tile<true, 0><<<dim3(2304 / 64, M_ / 64, 1), 256, 0, stream>>>(
        regA, C_, 0, 0, qkv_w, C_, 0, 0, nullptr, nullptr, 0,
        qkv, 3 * C_, 0, 0, M_, 3 * C_, C_, 1.0f);

    // 3) S = scale * q @ k^T  -> attn region (batched over 96 (b,h))
    gemm_tile<true, 0><<<dim3(N_ / 64, N_ / 64, B_ * H_), 256, 0, stream>>>(
        qkv,        3 * C_, (long)N_ * 3 * C_, D_,
        qkv + C_,   3 * C_, (long)N_ * 3 * C_, D_,
        nullptr, nullptr, 0,
        attn, N_, (long)H_ * N_ * N_, (long)N_ * N_,
        N_, N_, D_, 0.125f);

    // 4) softmax rows, in place
    softmax_kernel<<<B_ * H_ * N_, 256, 0, stream>>>(attn);

    // 5) head-mix + BN, in place  (attn region now holds attn_next, final)
    mixbn_kernel<<<M_, 256, 0, stream>>>(attn, conv_w, conv_b, bn_g, bn_b, bn_rm, bn_rv);

    // 6) O = attn @ v  -> regA, written directly in [B,N,C] layout
    gemm_tile<false, 0><<<dim3(1, N_ / 64, B_ * H_), 256, 0, stream>>>(
        attn, N_, (long)H_ * N_ * N_, (long)N_ * N_,
        qkv + 2 * C_, 3 * C_, (long)N_ * 3 * C_, D_,
        nullptr, nullptr, 0,
        regA, C_, (long)N_ * C_, D_,
        N_, D_, N_, 1.0f);

    // 7) x = inputs + O @ proj_w^T + proj_b -> regB
    gemm_tile<true, 0><<<dim3(C_ / 64, M_ / 64, 1), 256, 0, stream>>>(
        regA, C_, 0, 0, proj_w, C_, 0, 0, proj_b, inp, C_,
        regB, C_, 0, 0, M_, C_, C_, 1.0f);

    // 8) LN2: regB -> regA
    ln_kernel<<<M_, 256, 0, stream>>>(regB, ln2_g, ln2_b, regA);

    // 9) h = gelu(xln2 @ fc1_w^T + fc1_b) -> regH
    gemm_tile<true, 1><<<dim3(HID_ / 64, M_ / 64, 1), 256, 0, stream>>>(
        regA, C_, 0, 0, fc1_w, C_, 0, 0, fc1_b, nullptr, 0,
        regH, HID_, 0, 0, M_, HID_, C_, 1.0f);

    // 10) out = x + h @ fc2_w^T + fc2_b -> outx
    gemm_tile<true, 0><<<dim3(C_ / 64, M_ / 64, 1), 256, 0, stream>>>(
        regH, HID_, 0, 0, fc2_w, HID_, 0, 0, fc2_b, regB, C_,
        outx, C_, 0, 0, M_, C_, HID_, 1.0f);
}

// Round 2
// 735.144 us; speedup vs baseline: 4.0232x; 4.0232x over previous
//
#include <hip/hip_runtime.h>
#include <cmath>

#define B_   8
#define N_   1024
#define C_   768
#define H_   12
#define D_   64
#define HID_ 3072
#define M_   8192   // B_*N_

using frag  = __attribute__((ext_vector_type(8))) short;   // 8 bf16
using f32x4 = __attribute__((ext_vector_type(4))) float;
using s4v   = __attribute__((ext_vector_type(4))) short;

__device__ __forceinline__ short f2bf(float x) {
    union { float f; unsigned u; } v; v.f = x;
    unsigned r = (v.u + 0x7FFFu + ((v.u >> 16) & 1u)) >> 16;  // RNE
    return (short)r;
}
__device__ __forceinline__ float gelu_exact(float x) {
    return 0.5f * x * (1.0f + erff(x * 0.70710678118654752f));
}
__device__ __forceinline__ void gload16(const void* g, void* l) {
    __builtin_amdgcn_global_load_lds(
        (const __attribute__((address_space(1))) void*)g,
        (__attribute__((address_space(3))) void*)l, 16, 0, 0);
}

// ---------------- fp32 -> bf16 bulk convert ----------------
__global__ __launch_bounds__(256)
void cvt_bf16(const float* __restrict__ src, short* __restrict__ dst, int n)
{
    int i = (blockIdx.x * 256 + threadIdx.x) * 4;
    if (i < n) {
        float4 u = *(const float4*)(src + i);
        s4v s; s[0] = f2bf(u.x); s[1] = f2bf(u.y); s[2] = f2bf(u.z); s[3] = f2bf(u.w);
        *(s4v*)(dst + i) = s;
    }
}

// ---------------- LayerNorm fp32 -> bf16 ----------------
__global__ __launch_bounds__(256)
void ln_bf16(const float* __restrict__ x, const float* __restrict__ g,
             const float* __restrict__ b, short* __restrict__ y)
{
    __shared__ float red[256];
    const long row = blockIdx.x;
    const float* xr = x + row * C_;
    short* yr = y + row * C_;
    const int t = threadIdx.x;
    float v0 = xr[t], v1 = xr[t + 256], v2 = xr[t + 512];
    red[t] = v0 + v1 + v2;
    __syncthreads();
    for (int o = 128; o > 0; o >>= 1) { if (t < o) red[t] += red[t + o]; __syncthreads(); }
    const float mu = red[0] * (1.0f / 768.0f);
    __syncthreads();
    const float d0 = v0 - mu, d1 = v1 - mu, d2 = v2 - mu;
    red[t] = d0 * d0 + d1 * d1 + d2 * d2;
    __syncthreads();
    for (int o = 128; o > 0; o >>= 1) { if (t < o) red[t] += red[t + o]; __syncthreads(); }
    const float rstd = rsqrtf(red[0] * (1.0f / 768.0f) + 1e-5f);
    yr[t]       = f2bf(d0 * rstd * g[t]       + b[t]);
    yr[t + 256] = f2bf(d1 * rstd * g[t + 256] + b[t + 256]);
    yr[t + 512] = f2bf(d2 * rstd * g[t + 512] + b[t + 512]);
}

// ---------------- MFMA GEMM: C = alpha*A@B^T (+bias)(+res)(gelu) ----------------
// A: [M,K] bf16 (or fp32 if AF32, reg-staged+converted). B: [N,K] bf16.
// LDS tiles [rows][32] bf16, XOR-swizzled: physical slot = logical ^ ((row>>1)&3).
// Staged via global_load_lds (linear dest, pre-swizzled global source).
template<int BM, int BN, int WGM, int WGN, bool AF32, bool OUTF32, bool ACT_GELU>
__global__ __launch_bounds__(256)
void gemm_mfma(const void* __restrict__ Ap, int lda, long sAb, long sAh,
               const short* __restrict__ Bp, int ldb, long sBb, long sBh,
               const float* __restrict__ bias,
               const float* __restrict__ res, int ldres,
               void* __restrict__ Cp, int ldc, long sCb, long sCh,
               int K, float alpha)
{
    constexpr int FM = BM / (WGM * 16), FN = BN / (WGN * 16);
    constexpr int LA = BM / 16, LB = BN / 16;
    __shared__ short As[BM * 32];
    __shared__ short Bs[BN * 32];
    const int tid = threadIdx.x;
    const int wid = tid >> 6, lane = tid & 63;
    const int z = blockIdx.z, zb = z / H_, zh = z - zb * H_;
    const long m0 = (long)blockIdx.y * BM;
    const int  n0 = blockIdx.x * BN;
    const short* Bb = Bp + zb * sBb + zh * sBh + (long)n0 * ldb;
    const short* Abh = nullptr; const float* Afh = nullptr;
    if constexpr (AF32) Afh = (const float*)Ap + zb * sAb + zh * sAh + m0 * lda;
    else                Abh = (const short*)Ap + zb * sAb + zh * sAh + m0 * lda;
    f32x4 acc[FM][FN] = {};
    const int wr = wid / WGN, wc = wid - wr * WGN;

    for (int k0 = 0; k0 < K; k0 += 32) {
        if constexpr (!AF32) {
            for (int i = wid; i < LA; i += 4) {
                const int row = i * 16 + (lane >> 2);
                const int sl  = (lane & 3) ^ ((row >> 1) & 3);
                gload16(Abh + (long)row * lda + k0 + sl * 8, &As[i * 512]);
            }
        } else {
            const int r = tid >> 1, h2 = tid & 1;
            const float* sp = Afh + (long)r * lda + k0 + h2 * 16;
            float4 u0 = *(const float4*)(sp);
            float4 u1 = *(const float4*)(sp + 4);
            float4 u2 = *(const float4*)(sp + 8);
            float4 u3 = *(const float4*)(sp + 12);
            frag w0, w1;
            w0[0] = f2bf(u0.x); w0[1] = f2bf(u0.y); w0[2] = f2bf(u0.z); w0[3] = f2bf(u0.w);
            w0[4] = f2bf(u1.x); w0[5] = f2bf(u1.y); w0[6] = f2bf(u1.z); w0[7] = f2bf(u1.w);
            w1[0] = f2bf(u2.x); w1[1] = f2bf(u2.y); w1[2] = f2bf(u2.z); w1[3] = f2bf(u2.w);
            w1[4] = f2bf(u3.x); w1[5] = f2bf(u3.y); w1[6] = f2bf(u3.z); w1[7] = f2bf(u3.w);
            const int swz = (r >> 1) & 3;
            *(frag*)&As[r * 32 + ((2 * h2    ) ^ swz) * 8] = w0;
            *(frag*)&As[r * 32 + ((2 * h2 + 1) ^ swz) * 8] = w1;
        }
        for (int i = wid; i < LB; i += 4) {
            const int row = i * 16 + (lane >> 2);
            const int sl  = (lane & 3) ^ ((row >> 1) & 3);
            gload16(Bb + (long)row * ldb + k0 + sl * 8, &Bs[i * 512]);
        }
        __syncthreads();
        frag a[FM], b[FN];
        #pragma unroll
        for (int fm = 0; fm < FM; ++fm) {
            const int r = wr * FM * 16 + fm * 16 + (lane & 15);
            const int sl = (lane >> 4) ^ ((r >> 1) & 3);
            a[fm] = *(const frag*)&As[r * 32 + sl * 8];
        }
        #pragma unroll
        for (int fn = 0; fn < FN; ++fn) {
            const int r = wc * FN * 16 + fn * 16 + (lane & 15);
            const int sl = (lane >> 4) ^ ((r >> 1) & 3);
            b[fn] = *(const frag*)&Bs[r * 32 + sl * 8];
        }
        #pragma unroll
        for (int fm = 0; fm < FM; ++fm)
            #pragma unroll
            for (int fn = 0; fn < FN; ++fn)
                acc[fm][fn] = __builtin_amdgcn_mfma_f32_16x16x32_bf16(a[fm], b[fn], acc[fm][fn], 0, 0, 0);
        __syncthreads();
    }

    float* Cf = (float*)Cp; short* Cs = (short*)Cp;
    const long cbase = zb * sCb + zh * sCh;
    #pragma unroll
    for (int fm = 0; fm < FM; ++fm) {
        #pragma unroll
        for (int fn = 0; fn < FN; ++fn) {
            const long rg = m0 + wr * FM * 16 + fm * 16 + ((lane >> 4) * 4);
            const int  cg = n0 + wc * FN * 16 + fn * 16 + (lane & 15);
            const float bv = bias ? bias[cg] : 0.0f;
            #pragma unroll
            for (int q = 0; q < 4; ++q) {
                const long row = rg + q;
                float v = acc[fm][fn][q] * alpha + bv;
                if (res) v += res[row * (long)ldres + cg];
                if constexpr (ACT_GELU) v = gelu_exact(v);
                if constexpr (OUTF32) Cf[cbase + row * ldc + cg] = v;
                else                  Cs[cbase + row * ldc + cg] = f2bf(v);
            }
        }
    }
}

// ---------------- fused softmax + head-mix(1x1 conv) + BN, in place ----------------
// One block per (b,n); thread t owns m = t*4..t*4+3 across all 12 heads.
__global__ __launch_bounds__(256)
void smb_kernel(float* __restrict__ S,
                const float* __restrict__ cw, const float* __restrict__ cb,
                const float* __restrict__ bg, const float* __restrict__ bb,
                const float* __restrict__ brm, const float* __restrict__ brv)
{
    __shared__ float red[H_][264];
    __shared__ float w[H_][H_];
    __shared__ float cbias[H_], sc[H_], sh[H_];
    const int t = threadIdx.x;
    if (t < H_ * H_) w[t / H_][t % H_] = cw[t];
    if (t < H_) {
        cbias[t] = cb[t];
        const float s = bg[t] * rsqrtf(brv[t] + 1e-5f);
        sc[t] = s;
        sh[t] = bb[t] - brm[t] * s;
    }
    const long bn = blockIdx.x;
    const long b = bn >> 10, n = bn & 1023;
    float* base = S + b * (long)H_ * N_ * N_ + n * (long)N_ + t * 4;
    float4 p[H_];
    #pragma unroll
    for (int h = 0; h < H_; h++) p[h] = *(float4*)(base + (long)h * N_ * N_);
    // per-head max
    #pragma unroll
    for (int h = 0; h < H_; h++)
        red[h][t] = fmaxf(fmaxf(p[h].x, p[h].y), fmaxf(p[h].z, p[h].w));
    __syncthreads();
    for (int o = 128; o > 0; o >>= 1) {
        if (t < o) {
            #pragma unroll
            for (int h = 0; h < H_; h++) red[h][t] = fmaxf(red[h][t], red[h][t + o]);
        }
        __syncthreads();
    }
    float mx[H_];
    #pragma unroll
    for (int h = 0; h < H_; h++) mx[h] = red[h][0];
    __syncthreads();
    // exp + per-head sum
    #pragma unroll
    for (int h = 0; h < H_; h++) {
        p[h].x = __expf(p[h].x - mx[h]); p[h].y = __expf(p[h].y - mx[h]);
        p[h].z = __expf(p[h].z - mx[h]); p[h].w = __expf(p[h].w - mx[h]);
        red[h][t] = p[h].x + p[h].y + p[h].z + p[h].w;
    }
    __syncthreads();
    for (int o = 128; o > 0; o >>= 1) {
        if (t < o) {
            #pragma unroll
            for (int h = 0; h < H_; h++) red[h][t] += red[h][t + o];
        }
        __syncthreads();
    }
    #pragma unroll
    for (int h = 0; h < H_; h++) {
        const float inv = 1.0f / red[h][0];
        p[h].x *= inv; p[h].y *= inv; p[h].z *= inv; p[h].w *= inv;
    }
    // head mix + BN
    #pragma unroll
    for (int o = 0; o < H_; o++) {
        float4 a; a.x = cbias[o]; a.y = cbias[o]; a.z = cbias[o]; a.w = cbias[o];
        #pragma unroll
        for (int h = 0; h < H_; h++) {
            const float wv = w[o][h];
            a.x += wv * p[h].x; a.y += wv * p[h].y;
            a.z += wv * p[h].z; a.w += wv * p[h].w;
        }
        a.x = a.x * sc[o] + sh[o]; a.y = a.y * sc[o] + sh[o];
        a.z = a.z * sc[o] + sh[o]; a.w = a.w * sc[o] + sh[o];
        *(float4*)(base + (long)o * N_ * N_) = a;
    }
}

// ---------------- v transpose: qkv bf16 [B*N,2304] -> vT [B*H][64][1024] ----------------
__global__ __launch_bounds__(256)
void vtrans(const short* __restrict__ qkv, short* __restrict__ vT)
{
    __shared__ short tile[64][72];
    const int bh = blockIdx.x;
    const int n0 = blockIdx.y * 64;
    const int b = bh / H_, h = bh - b * H_;
    const short* src = qkv + (long)b * N_ * (3 * C_) + 2 * C_ + h * D_;
    const int t = threadIdx.x;
    {
        const int r = t >> 2, c = (t & 3) * 16;
        const short* sp = src + (long)(n0 + r) * (3 * C_) + c;
        #pragma unroll
        for (int j = 0; j < 16; j++) tile[r][c + j] = sp[j];
    }
    __syncthreads();
    {
        const int d = t >> 2, c = (t & 3) * 16;
        short* dp = vT + (long)bh * (D_ * N_) + (long)d * N_ + n0 + c;
        #pragma unroll
        for (int j = 0; j < 16; j++) dp[j] = tile[c + j][d];
    }
}

// ---------------- launch ----------------
extern "C" void kernel_launch(void* const* d_in, const int* in_sizes, int n_in,
                              void* d_out, int out_size, void* d_ws, size_t ws_size,
                              hipStream_t stream)
{
    const float* inp    = (const float*)d_in[0];
    const float* ln1_g  = (const float*)d_in[1];
    const float* ln1_b  = (const float*)d_in[2];
    const float* qkv_w  = (const float*)d_in[3];
    const float* conv_w = (const float*)d_in[4];
    const float* conv_b = (const float*)d_in[5];
    const float* bn_g   = (const float*)d_in[6];
    const float* bn_b   = (const float*)d_in[7];
    const float* bn_rm  = (const float*)d_in[8];
    const float* bn_rv  = (const float*)d_in[9];
    const float* proj_w = (const float*)d_in[10];
    const float* proj_b = (const float*)d_in[11];
    const float* ln2_g  = (const float*)d_in[12];
    const float* ln2_b  = (const float*)d_in[13];
    const float* fc1_w  = (const float*)d_in[14];
    const float* fc1_b  = (const float*)d_in[15];
    const float* fc2_w  = (const float*)d_in[16];
    const float* fc2_b  = (const float*)d_in[17];

    float* outx = (float*)d_out;
    float* attn = outx + (long)M_ * C_;

    char* w = (char*)d_ws;
    short* wqkv  = (short*)w;  w += (long)3 * C_ * C_ * 2;
    short* wproj = (short*)w;  w += (long)C_ * C_ * 2;
    short* wfc1  = (short*)w;  w += (long)HID_ * C_ * 2;
    short* wfc2  = (short*)w;  w += (long)C_ * HID_ * 2;
    short* xln   = (short*)w;  w += (long)M_ * C_ * 2;
    short* qkvb  = (short*)w;                              // reused as h later
    short* hbuf  = qkvb;       w += (long)M_ * HID_ * 2;   // max(qkv, h) region
    short* vT    = (short*)w;  w += (long)B_ * H_ * D_ * N_ * 2;
    short* Obf   = (short*)w;  w += (long)M_ * C_ * 2;
    float* xres  = (float*)w;  w += (long)M_ * C_ * 4;

    // weights -> bf16
    cvt_bf16<<<(3 * C_ * C_) / 1024, 256, 0, stream>>>(qkv_w, wqkv, 3 * C_ * C_);
    cvt_bf16<<<(C_ * C_) / 1024,     256, 0, stream>>>(proj_w, wproj, C_ * C_);
    cvt_bf16<<<(HID_ * C_) / 1024,   256, 0, stream>>>(fc1_w, wfc1, HID_ * C_);
    cvt_bf16<<<(C_ * HID_) / 1024,   256, 0, stream>>>(fc2_w, wfc2, C_ * HID_);

    // 1) LN1 -> xln (bf16)
    ln_bf16<<<M_, 256, 0, stream>>>(inp, ln1_g, ln1_b, xln);

    // 2) qkv = xln @ qkv_w^T -> bf16 [8192,2304]
    gemm_mfma<128, 128, 2, 2, false, false, false><<<dim3(18, 64, 1), 256, 0, stream>>>(
        xln, C_, 0, 0, wqkv, C_, 0, 0, nullptr, nullptr, 0,
        qkvb, 3 * C_, 0, 0, C_, 1.0f);

    // 3) vT = transpose(v)
    vtrans<<<dim3(B_ * H_, 16), 256, 0, stream>>>(qkvb, vT);

    // 4) S = 0.125 * q @ k^T -> fp32 attn (batched 96)
    gemm_mfma<128, 128, 2, 2, false, true, false><<<dim3(8, 8, 96), 256, 0, stream>>>(
        qkvb,      3 * C_, (long)N_ * 3 * C_, D_,
        qkvb + C_, 3 * C_, (long)N_ * 3 * C_, D_,
        nullptr, nullptr, 0,
        attn, N_, (long)H_ * N_ * N_, (long)N_ * N_, D_, 0.125f);

    // 5) softmax + head-mix + BN, in place (attn now final attn_next)
    smb_kernel<<<M_, 256, 0, stream>>>(attn, conv_w, conv_b, bn_g, bn_b, bn_rm, bn_rv);

    // 6) O = attn @ v -> bf16 [B,N,C] layout
    gemm_mfma<128, 64, 4, 1, true, false, false><<<dim3(1, 8, 96), 256, 0, stream>>>(
        attn, N_, (long)H_ * N_ * N_, (long)N_ * N_,
        vT, N_, (long)H_ * D_ * N_, (long)D_ * N_,
        nullptr, nullptr, 0,
        Obf, C_, (long)N_ * C_, D_, N_, 1.0f);

    // 7) x = inputs + O @ proj_w^T + proj_b -> fp32
    gemm_mfma<128, 128, 2, 2, false, true, false><<<dim3(6, 64, 1), 256, 0, stream>>>(
        Obf, C_, 0, 0, wproj, C_, 0, 0, proj_b, inp, C_,
        xres, C_, 0, 0, C_, 1.0f);

    // 8) LN2 -> xln (bf16, reuse)
    ln_bf16<<<M_, 256, 0, stream>>>(xres, ln2_g, ln2_b, xln);

    // 9) h = gelu(xln @ fc1_w^T + fc1_b) -> bf16
    gemm_mfma<128, 128, 2, 2, false, false, true><<<dim3(24, 64, 1), 256, 0, stream>>>(
        xln, C_, 0, 0, wfc1, C_, 0, 0, fc1_b, nullptr, 0,
        hbuf, HID_, 0, 0, C_, 1.0f);

    // 10) out = x + h @ fc2_w^T + fc2_b -> fp32
    gemm_mfma<128, 128, 2, 2, false, true, false><<<dim3(6, 64, 1), 256, 0, stream>>>(
        hbuf, HID_, 0, 0, wfc2, HID_, 0, 0, fc2_b, xres, C_,
        outx, C_, 0, 0, HID_, 1.0f);
}